// Round 6
// baseline (51.832 us; speedup 1.0000x reference)
//
#include <hip/hip_runtime.h>

// 1D cubic B-spline field evaluation.
//   dx = 2/(num_cp-3); origin = -1-dx
//   tt = t - origin - dx; q = tt/dx; idx = floor(q); u = q - idx
//   out = sum_{k=0..3} w_k(u) * phi[clamp(idx+k, 0, num_cp-1)]
//
// R2: L1 divergent-gather serialization was the wall (166us). R3: LDS staging
// -> 52us. R5: block=512 + ds_read2 fast path + NT stores -> 47.9us.
// R6: grid=1024 (exactly 4 resident blocks/CU -> one phi staging per slot,
// no mid-kernel re-staging batches) + 2x unroll for doubled VMEM in flight.

#define MAX_CP_LDS 8192
#define BLOCK 512
#define GRID 1024   // 256 CU x 4 blocks (32 KiB LDS each -> all resident)

typedef float f4v __attribute__((ext_vector_type(4)));  // native vec for nontemporal builtin

__device__ __forceinline__ float bspline_eval_lds(float tval, const float* sPhi,
                                                  float origin, float dx, float inv_dx,
                                                  int num_cp) {
    float tt = (tval - origin) - dx;   // matches reference op order
    float q  = tt * inv_dx;
    float fidx = floorf(q);
    float u  = q - fidx;
    int idx = (int)fidx;
    int hi  = num_cp - 1;

    float v0, v1, v2, v3;
    if (__builtin_expect((unsigned)idx <= (unsigned)(hi - 3), 1)) {
        // In-range (always true for the bench data): consecutive reads,
        // compiler merges into ds_read2_b32 pairs.
        v0 = sPhi[idx];
        v1 = sPhi[idx + 1];
        v2 = sPhi[idx + 2];
        v3 = sPhi[idx + 3];
    } else {
        int i0 = min(max(idx,     0), hi);
        int i1 = min(max(idx + 1, 0), hi);
        int i2 = min(max(idx + 2, 0), hi);
        int i3 = min(max(idx + 3, 0), hi);
        v0 = sPhi[i0]; v1 = sPhi[i1]; v2 = sPhi[i2]; v3 = sPhi[i3];
    }

    float u2 = u * u;
    float u3 = u2 * u;
    float om = 1.0f - u;
    const float sixth = 1.0f / 6.0f;
    float w0 = om * om * om * sixth;
    float w3 = u3 * sixth;
    float w1 = fmaf(0.5f, u3, fmaf(-1.0f, u2, 2.0f / 3.0f)); // (3u^3-6u^2+4)/6
    float w2 = 1.0f - w0 - w1 - w3;                          // partition of unity

    return fmaf(w0, v0, fmaf(w1, v1, fmaf(w2, v2, w3 * v3)));
}

__global__ __launch_bounds__(BLOCK) void bspline1d_lds_kernel(
    const float* __restrict__ t,
    const float* __restrict__ phi,
    float* __restrict__ out,
    int num_cp, int n)
{
    __shared__ float sPhi[MAX_CP_LDS];

    // Stage phi into LDS with float4 loads: 8192 floats / 512 thr = 4 float4 each.
    {
        const float4* __restrict__ p4 = reinterpret_cast<const float4*>(phi);
        float4* s4 = reinterpret_cast<float4*>(sPhi);
        const int nc4 = num_cp >> 2;
        for (int j = threadIdx.x; j < nc4; j += blockDim.x) {
            s4[j] = p4[j];
        }
        for (int j = (nc4 << 2) + threadIdx.x; j < num_cp; j += blockDim.x) {
            sPhi[j] = phi[j];
        }
    }
    __syncthreads();

    const float dx     = 2.0f / (float)(num_cp - 3);
    const float origin = -1.0f - dx;
    const float inv_dx = (float)(num_cp - 3) * 0.5f;  // 1/dx

    const int tid    = blockIdx.x * blockDim.x + threadIdx.x;
    const int stride = gridDim.x * blockDim.x;
    const int n4     = n >> 2;

    const float4* __restrict__ t4 = reinterpret_cast<const float4*>(t);
    f4v* __restrict__ o4          = reinterpret_cast<f4v*>(out);

    int i = tid;
    // 2x unroll: two independent 16B loads in flight per iteration.
    for (; i + stride < n4; i += 2 * stride) {
        float4 ta = t4[i];
        float4 tb = t4[i + stride];
        f4v ra, rb;
        ra.x = bspline_eval_lds(ta.x, sPhi, origin, dx, inv_dx, num_cp);
        ra.y = bspline_eval_lds(ta.y, sPhi, origin, dx, inv_dx, num_cp);
        ra.z = bspline_eval_lds(ta.z, sPhi, origin, dx, inv_dx, num_cp);
        ra.w = bspline_eval_lds(ta.w, sPhi, origin, dx, inv_dx, num_cp);
        rb.x = bspline_eval_lds(tb.x, sPhi, origin, dx, inv_dx, num_cp);
        rb.y = bspline_eval_lds(tb.y, sPhi, origin, dx, inv_dx, num_cp);
        rb.z = bspline_eval_lds(tb.z, sPhi, origin, dx, inv_dx, num_cp);
        rb.w = bspline_eval_lds(tb.w, sPhi, origin, dx, inv_dx, num_cp);
        __builtin_nontemporal_store(ra, &o4[i]);           // out never re-read
        __builtin_nontemporal_store(rb, &o4[i + stride]);
    }
    for (; i < n4; i += stride) {
        float4 tv = t4[i];
        f4v r;
        r.x = bspline_eval_lds(tv.x, sPhi, origin, dx, inv_dx, num_cp);
        r.y = bspline_eval_lds(tv.y, sPhi, origin, dx, inv_dx, num_cp);
        r.z = bspline_eval_lds(tv.z, sPhi, origin, dx, inv_dx, num_cp);
        r.w = bspline_eval_lds(tv.w, sPhi, origin, dx, inv_dx, num_cp);
        __builtin_nontemporal_store(r, &o4[i]);
    }

    for (int j = (n4 << 2) + tid; j < n; j += stride) {
        float v = bspline_eval_lds(t[j], sPhi, origin, dx, inv_dx, num_cp);
        __builtin_nontemporal_store(v, &out[j]);
    }
}

// Fallback for num_cp > LDS capacity (not expected here): gather from global.
__global__ __launch_bounds__(BLOCK) void bspline1d_global_kernel(
    const float* __restrict__ t,
    const float* __restrict__ phi,
    float* __restrict__ out,
    int num_cp, int n)
{
    const float dx     = 2.0f / (float)(num_cp - 3);
    const float origin = -1.0f - dx;
    const float inv_dx = (float)(num_cp - 3) * 0.5f;

    const int tid    = blockIdx.x * blockDim.x + threadIdx.x;
    const int stride = gridDim.x * blockDim.x;
    for (int i = tid; i < n; i += stride) {
        out[i] = bspline_eval_lds(t[i], phi, origin, dx, inv_dx, num_cp);
    }
}

extern "C" void kernel_launch(void* const* d_in, const int* in_sizes, int n_in,
                              void* d_out, int out_size, void* d_ws, size_t ws_size,
                              hipStream_t stream) {
    const float* t   = (const float*)d_in[0];
    const float* phi = (const float*)d_in[1];
    float* out       = (float*)d_out;
    const int n      = in_sizes[0];
    const int num_cp = in_sizes[1];

    if (num_cp <= MAX_CP_LDS) {
        bspline1d_lds_kernel<<<GRID, BLOCK, 0, stream>>>(t, phi, out, num_cp, n);
    } else {
        bspline1d_global_kernel<<<2048, BLOCK, 0, stream>>>(t, phi, out, num_cp, n);
    }
}

// Round 7
// 49.985 us; speedup vs baseline: 1.0370x; 1.0370x over previous
//
#include <hip/hip_runtime.h>
#include <hip/hip_fp16.h>

// 1D cubic B-spline field evaluation.
//   dx = 2/(num_cp-3); origin = -1-dx
//   tt = t - origin - dx; q = tt/dx; idx = floor(q); u = q - idx
//   out = sum_{k=0..3} w_k(u) * phi[clamp(idx+k, 0, num_cp-1)]
//
// R2: L1 divergent-gather serialization (166us). R3: LDS staging -> 52us.
// R5: block=512 + ds_read2 fast path + NT stores -> 47.9us. R6 (grid1024+
// unroll2) regressed -> LDS pipe is the serial resource (~27us/CU busy).
// R7: parity-shifted packed fp16 tables: A[j]=(phi[2j],phi[2j+1]),
// B[j]=(phi[2j+1],phi[2j+2]); any idx's 4 taps = 2 consecutive dwords of
// table (idx&1) -> ONE ds_read2_b32 per point (was two). fp16 quant error
// ~2e-3 << 5.5e-2 threshold.

#define MAX_CP_LDS 8192
#define BLOCK 512
#define GRID 2048

typedef float f4v __attribute__((ext_vector_type(4)));  // native vec for nontemporal builtin

__device__ __forceinline__ float bspline_eval_packed(
    float tval, const __half2* sTab, int nw,
    float origin, float dx, float inv_dx, int num_cp,
    const float* __restrict__ gphi)
{
    float tt = (tval - origin) - dx;   // matches reference op order
    float q  = tt * inv_dx;
    float fidx = floorf(q);
    float u  = q - fidx;
    int idx = (int)fidx;
    int hi  = num_cp - 1;

    float v0, v1, v2, v3;
    if (__builtin_expect((unsigned)idx <= (unsigned)(hi - 3), 1)) {
        // 4 taps = 2 consecutive half2 words of table (idx&1): one ds_read2_b32.
        int o = (idx >> 1) + ((idx & 1) ? nw : 0);
        __half2 a = sTab[o];
        __half2 b = sTab[o + 1];
        v0 = __half2float(a.x);
        v1 = __half2float(a.y);
        v2 = __half2float(b.x);
        v3 = __half2float(b.y);
    } else {
        // Rare/never for bench data: exact f32 path from global (L2-cached).
        int i0 = min(max(idx,     0), hi);
        int i1 = min(max(idx + 1, 0), hi);
        int i2 = min(max(idx + 2, 0), hi);
        int i3 = min(max(idx + 3, 0), hi);
        v0 = gphi[i0]; v1 = gphi[i1]; v2 = gphi[i2]; v3 = gphi[i3];
    }

    float u2 = u * u;
    float u3 = u2 * u;
    float om = 1.0f - u;
    const float sixth = 1.0f / 6.0f;
    float w0 = om * om * om * sixth;
    float w3 = u3 * sixth;
    float w1 = fmaf(0.5f, u3, fmaf(-1.0f, u2, 2.0f / 3.0f)); // (3u^3-6u^2+4)/6
    float w2 = 1.0f - w0 - w1 - w3;                          // partition of unity

    return fmaf(w0, v0, fmaf(w1, v1, fmaf(w2, v2, w3 * v3)));
}

__global__ __launch_bounds__(BLOCK) void bspline1d_lds_kernel(
    const float* __restrict__ t,
    const float* __restrict__ phi,
    float* __restrict__ out,
    int num_cp, int n)
{
    __shared__ __half2 sTab[MAX_CP_LDS];  // [0,nw)=A table, [nw,2nw)=B table; 32 KiB

    const int hi = num_cp - 1;
    const int nw = (num_cp + 1) >> 1;

    // Stage packed tables: A[j]=(phi[2j],phi[2j+1]), B[j]=(phi[2j+1],phi[2j+2]).
    for (int j = threadIdx.x; j < nw; j += blockDim.x) {
        float p0 = phi[min(2 * j,     hi)];
        float p1 = phi[min(2 * j + 1, hi)];
        float p2 = phi[min(2 * j + 2, hi)];
        sTab[j]      = __halves2half2(__float2half(p0), __float2half(p1));
        sTab[j + nw] = __halves2half2(__float2half(p1), __float2half(p2));
    }
    __syncthreads();

    const float dx     = 2.0f / (float)(num_cp - 3);
    const float origin = -1.0f - dx;
    const float inv_dx = (float)(num_cp - 3) * 0.5f;  // 1/dx

    const int tid    = blockIdx.x * blockDim.x + threadIdx.x;
    const int stride = gridDim.x * blockDim.x;
    const int n4     = n >> 2;

    const float4* __restrict__ t4 = reinterpret_cast<const float4*>(t);
    f4v* __restrict__ o4          = reinterpret_cast<f4v*>(out);

    for (int i = tid; i < n4; i += stride) {
        float4 tv = t4[i];
        f4v r;
        r.x = bspline_eval_packed(tv.x, sTab, nw, origin, dx, inv_dx, num_cp, phi);
        r.y = bspline_eval_packed(tv.y, sTab, nw, origin, dx, inv_dx, num_cp, phi);
        r.z = bspline_eval_packed(tv.z, sTab, nw, origin, dx, inv_dx, num_cp, phi);
        r.w = bspline_eval_packed(tv.w, sTab, nw, origin, dx, inv_dx, num_cp, phi);
        __builtin_nontemporal_store(r, &o4[i]);  // out never re-read
    }

    for (int j = (n4 << 2) + tid; j < n; j += stride) {
        float v = bspline_eval_packed(t[j], sTab, nw, origin, dx, inv_dx, num_cp, phi);
        __builtin_nontemporal_store(v, &out[j]);
    }
}

// Fallback for num_cp > LDS capacity (not expected here): gather from global, f32 exact.
__global__ __launch_bounds__(BLOCK) void bspline1d_global_kernel(
    const float* __restrict__ t,
    const float* __restrict__ phi,
    float* __restrict__ out,
    int num_cp, int n)
{
    const float dx     = 2.0f / (float)(num_cp - 3);
    const float origin = -1.0f - dx;
    const float inv_dx = (float)(num_cp - 3) * 0.5f;
    const int hi = num_cp - 1;

    const int tid    = blockIdx.x * blockDim.x + threadIdx.x;
    const int stride = gridDim.x * blockDim.x;
    for (int i = tid; i < n; i += stride) {
        float tt = (t[i] - origin) - dx;
        float q  = tt * inv_dx;
        float fidx = floorf(q);
        float u  = q - fidx;
        int idx = (int)fidx;
        int i0 = min(max(idx,     0), hi);
        int i1 = min(max(idx + 1, 0), hi);
        int i2 = min(max(idx + 2, 0), hi);
        int i3 = min(max(idx + 3, 0), hi);
        float v0 = phi[i0], v1 = phi[i1], v2 = phi[i2], v3 = phi[i3];
        float u2 = u * u, u3 = u2 * u, om = 1.0f - u;
        const float sixth = 1.0f / 6.0f;
        float w0 = om * om * om * sixth;
        float w3 = u3 * sixth;
        float w1 = fmaf(0.5f, u3, fmaf(-1.0f, u2, 2.0f / 3.0f));
        float w2 = 1.0f - w0 - w1 - w3;
        out[i] = fmaf(w0, v0, fmaf(w1, v1, fmaf(w2, v2, w3 * v3)));
    }
}

extern "C" void kernel_launch(void* const* d_in, const int* in_sizes, int n_in,
                              void* d_out, int out_size, void* d_ws, size_t ws_size,
                              hipStream_t stream) {
    const float* t   = (const float*)d_in[0];
    const float* phi = (const float*)d_in[1];
    float* out       = (float*)d_out;
    const int n      = in_sizes[0];
    const int num_cp = in_sizes[1];

    if (num_cp <= MAX_CP_LDS) {
        bspline1d_lds_kernel<<<GRID, BLOCK, 0, stream>>>(t, phi, out, num_cp, n);
    } else {
        bspline1d_global_kernel<<<GRID, BLOCK, 0, stream>>>(t, phi, out, num_cp, n);
    }
}

// Round 8
// 48.271 us; speedup vs baseline: 1.0738x; 1.0355x over previous
//
#include <hip/hip_runtime.h>

// 1D cubic B-spline field evaluation.
//   dx = 2/(num_cp-3); origin = -1-dx
//   tt = t - origin - dx; q = tt/dx; idx = floor(q); u = q - idx
//   out = sum_{k=0..3} w_k(u) * phi[clamp(idx+k, 0, num_cp-1)]
//
// R2: L1 divergent-gather serialization (166us). R3: LDS staging -> 52us.
// R5: block=512 + ds_read2 fast path + NT stores -> 47.9us (best).
// R6 (grid1024+unroll) and R7 (halved LDS traffic) both flat -> NOT LDS-bound.
// R8 theory: VMEM latency-bound (Little's law: need ~22KB in flight/CU, the
// serial load->compute->store loop gives barely that). Fix: explicit 2-deep
// prefetch pipeline so each wave keeps 2 independent t-loads in flight and
// compute hides under load latency.

#define MAX_CP_LDS 8192
#define BLOCK 512
#define GRID 2048

typedef float f4v __attribute__((ext_vector_type(4)));  // native vec for nontemporal builtin

__device__ __forceinline__ float bspline_eval_lds(float tval, const float* sPhi,
                                                  float origin, float dx, float inv_dx,
                                                  int num_cp) {
    float tt = (tval - origin) - dx;   // matches reference op order
    float q  = tt * inv_dx;
    float fidx = floorf(q);
    float u  = q - fidx;
    int idx = (int)fidx;
    int hi  = num_cp - 1;

    float v0, v1, v2, v3;
    if (__builtin_expect((unsigned)idx <= (unsigned)(hi - 3), 1)) {
        // In-range (always true for the bench data): consecutive reads,
        // compiler merges into ds_read2_b32 pairs.
        v0 = sPhi[idx];
        v1 = sPhi[idx + 1];
        v2 = sPhi[idx + 2];
        v3 = sPhi[idx + 3];
    } else {
        int i0 = min(max(idx,     0), hi);
        int i1 = min(max(idx + 1, 0), hi);
        int i2 = min(max(idx + 2, 0), hi);
        int i3 = min(max(idx + 3, 0), hi);
        v0 = sPhi[i0]; v1 = sPhi[i1]; v2 = sPhi[i2]; v3 = sPhi[i3];
    }

    float u2 = u * u;
    float u3 = u2 * u;
    float om = 1.0f - u;
    const float sixth = 1.0f / 6.0f;
    float w0 = om * om * om * sixth;
    float w3 = u3 * sixth;
    float w1 = fmaf(0.5f, u3, fmaf(-1.0f, u2, 2.0f / 3.0f)); // (3u^3-6u^2+4)/6
    float w2 = 1.0f - w0 - w1 - w3;                          // partition of unity

    return fmaf(w0, v0, fmaf(w1, v1, fmaf(w2, v2, w3 * v3)));
}

__device__ __forceinline__ f4v eval4(float4 tv, const float* sPhi,
                                     float origin, float dx, float inv_dx, int num_cp) {
    f4v r;
    r.x = bspline_eval_lds(tv.x, sPhi, origin, dx, inv_dx, num_cp);
    r.y = bspline_eval_lds(tv.y, sPhi, origin, dx, inv_dx, num_cp);
    r.z = bspline_eval_lds(tv.z, sPhi, origin, dx, inv_dx, num_cp);
    r.w = bspline_eval_lds(tv.w, sPhi, origin, dx, inv_dx, num_cp);
    return r;
}

__global__ __launch_bounds__(BLOCK) void bspline1d_lds_kernel(
    const float* __restrict__ t,
    const float* __restrict__ phi,
    float* __restrict__ out,
    int num_cp, int n)
{
    __shared__ float sPhi[MAX_CP_LDS];

    // Stage phi into LDS with float4 loads: 8192 floats / 512 thr = 4 float4 each.
    {
        const float4* __restrict__ p4 = reinterpret_cast<const float4*>(phi);
        float4* s4 = reinterpret_cast<float4*>(sPhi);
        const int nc4 = num_cp >> 2;
        for (int j = threadIdx.x; j < nc4; j += blockDim.x) {
            s4[j] = p4[j];
        }
        for (int j = (nc4 << 2) + threadIdx.x; j < num_cp; j += blockDim.x) {
            sPhi[j] = phi[j];
        }
    }
    __syncthreads();

    const float dx     = 2.0f / (float)(num_cp - 3);
    const float origin = -1.0f - dx;
    const float inv_dx = (float)(num_cp - 3) * 0.5f;  // 1/dx

    const int tid    = blockIdx.x * blockDim.x + threadIdx.x;
    const int stride = gridDim.x * blockDim.x;
    const int n4     = n >> 2;

    const float4* __restrict__ t4 = reinterpret_cast<const float4*>(t);
    f4v* __restrict__ o4          = reinterpret_cast<f4v*>(out);

    // 2-deep software pipeline: keep two independent 16B loads in flight per
    // wave; compute of tv0 hides under the latency of the i+2*stride load.
    int i = tid;
    if (i < n4) {
        float4 tv0 = t4[i];
        if (i + stride < n4) {
            float4 tv1 = t4[i + stride];
            for (; i + 2 * stride < n4; i += stride) {
                float4 tn = t4[i + 2 * stride];   // issue before computing tv0
                f4v r = eval4(tv0, sPhi, origin, dx, inv_dx, num_cp);
                __builtin_nontemporal_store(r, &o4[i]);  // out never re-read
                tv0 = tv1;
                tv1 = tn;
            }
            f4v r = eval4(tv0, sPhi, origin, dx, inv_dx, num_cp);
            __builtin_nontemporal_store(r, &o4[i]);
            tv0 = tv1;
            i += stride;
        }
        f4v r = eval4(tv0, sPhi, origin, dx, inv_dx, num_cp);
        __builtin_nontemporal_store(r, &o4[i]);
    }

    for (int j = (n4 << 2) + tid; j < n; j += stride) {
        float v = bspline_eval_lds(t[j], sPhi, origin, dx, inv_dx, num_cp);
        __builtin_nontemporal_store(v, &out[j]);
    }
}

// Fallback for num_cp > LDS capacity (not expected here): gather from global.
__global__ __launch_bounds__(BLOCK) void bspline1d_global_kernel(
    const float* __restrict__ t,
    const float* __restrict__ phi,
    float* __restrict__ out,
    int num_cp, int n)
{
    const float dx     = 2.0f / (float)(num_cp - 3);
    const float origin = -1.0f - dx;
    const float inv_dx = (float)(num_cp - 3) * 0.5f;

    const int tid    = blockIdx.x * blockDim.x + threadIdx.x;
    const int stride = gridDim.x * blockDim.x;
    for (int i = tid; i < n; i += stride) {
        out[i] = bspline_eval_lds(t[i], phi, origin, dx, inv_dx, num_cp);
    }
}

extern "C" void kernel_launch(void* const* d_in, const int* in_sizes, int n_in,
                              void* d_out, int out_size, void* d_ws, size_t ws_size,
                              hipStream_t stream) {
    const float* t   = (const float*)d_in[0];
    const float* phi = (const float*)d_in[1];
    float* out       = (float*)d_out;
    const int n      = in_sizes[0];
    const int num_cp = in_sizes[1];

    if (num_cp <= MAX_CP_LDS) {
        bspline1d_lds_kernel<<<GRID, BLOCK, 0, stream>>>(t, phi, out, num_cp, n);
    } else {
        bspline1d_global_kernel<<<GRID, BLOCK, 0, stream>>>(t, phi, out, num_cp, n);
    }
}